// Round 1
// baseline (347.242 us; speedup 1.0000x reference)
//
#include <hip/hip_runtime.h>

// Superpixel max-pool: out[b][c][k] = max over pixels with spx[b,h,w]==k of img[b][c][h,w].
// LDS privatization, exclusive output ownership (512 blocks = 8 batches x 64 channel-pairs;
// each block owns out[b][c0:c0+2][:] -> no global atomics, no init pass).
//
// Session evidence (R1-R4): kernel dispatch never appears in rocprof top-5 (all 5 are the
// harness's 1 GiB d_ws re-poison fills @160us) => kernel itself is ~55us of the ~343us
// metric; the rest is fixed restore/poison overhead. LDS atomics are NOT the bottleneck
// (R2 lane-masking, R3 ballot-compaction: both neutral). Deeper VMEM batching is NOT the
// bottleneck (R4 unroll-2 batched loads: neutral -- 32 waves/CU already saturate TLP).
//
// R5: XCD-aware block swizzle. 8 batches == 8 XCDs. Default round-robin dispatch scatters
// the 64 blocks sharing one batch's 256 KB label array across all 8 XCD L2s -> 16 MB of
// label HBM traffic instead of 2 MB. Mapping b = blockIdx & 7 puts all 64 channel-group
// blocks of batch b on XCD b (blockIdx%8 -> XCD round-robin, HW-verified dispatch order),
// giving 64x label reuse in that XCD's private 4 MB L2. Nontemporal img loads are KEPT:
// img has zero reuse and bypassing L2 protects label residency.

#define NTHREADS 1024

constexpr int B_ = 8, C_ = 128, H_ = 256, W_ = 256, K_ = 1024;
constexpr int HW_ = H_ * W_;        // 65536
constexpr int CSUB = 2;             // channels per block
constexpr int CGRP = C_ / CSUB;     // 64 channel-groups per batch
constexpr int STRIDE = 3;           // odd -> (label*3+c)%32 spreads all 32 LDS banks
constexpr int NXCD = 8;             // batches == XCDs: b = blockIdx & 7 pins batch->XCD

typedef float  fx4 __attribute__((ext_vector_type(4)));  // native vec: ok for nontemporal
typedef int    ix4 __attribute__((ext_vector_type(4)));

// order-preserving float<->uint: monotone, so uint max == float max (bitwise exact)
__device__ __forceinline__ unsigned f2o(float f) {
    unsigned u = __float_as_uint(f);
    return u ^ (unsigned)(((int)u >> 31) | (int)0x80000000);
}
__device__ __forceinline__ float o2f(unsigned o) {
    return __uint_as_float(o ^ (((int)o >= 0) ? 0xFFFFFFFFu : 0x80000000u));
}

__global__ __launch_bounds__(NTHREADS) void SupPixPool_25366076850473_kernel(
    const float* __restrict__ img, const int* __restrict__ spx, float* __restrict__ out)
{
    __shared__ unsigned smax[K_ * STRIDE];   // 12 KB -> 2 blocks/CU, 32 waves/CU
    const int tid = threadIdx.x;

    // init to f2o(-inf) = 0x007FFFFF so empty segments produce -inf (segment_max semantics)
    for (int i = tid; i < K_ * STRIDE; i += NTHREADS)
        smax[i] = 0x007FFFFFu;
    __syncthreads();

    // XCD swizzle: blockIdx%8 -> XCD round-robin, so batch b owns XCD b and its 64
    // channel-group blocks share one L2 copy of the 256 KB label array.
    const int b  = blockIdx.x & (NXCD - 1);
    const int cg = blockIdx.x >> 3;          // 0..63
    const int c0 = cg * CSUB;

    const ix4* lab4 = (const ix4*)(spx + (size_t)b * HW_);
    const fx4* img0 = (const fx4*)(img + ((size_t)(b * C_ + c0)) * HW_);
    const fx4* img1 = (const fx4*)(img + ((size_t)(b * C_ + c0 + 1)) * HW_);
    constexpr int NV = HW_ / 4;              // 16384 vec4 groups; 16 strides -> 8 unroll-2 iters

    for (int v = tid; v < NV; v += 2 * NTHREADS) {
        const int v2 = v + NTHREADS;
        // batch all 6 vector loads up-front so vmcnt waits pipeline across both halves
        ix4 labA = lab4[v];
        ix4 labB = lab4[v2];
        fx4 xA0  = __builtin_nontemporal_load(&img0[v]);
        fx4 xA1  = __builtin_nontemporal_load(&img1[v]);
        fx4 xB0  = __builtin_nontemporal_load(&img0[v2]);
        fx4 xB1  = __builtin_nontemporal_load(&img1[v2]);

        int aA0 = labA.x * STRIDE, aA1 = labA.y * STRIDE,
            aA2 = labA.z * STRIDE, aA3 = labA.w * STRIDE;
        atomicMax(&smax[aA0],     f2o(xA0.x));
        atomicMax(&smax[aA1],     f2o(xA0.y));
        atomicMax(&smax[aA2],     f2o(xA0.z));
        atomicMax(&smax[aA3],     f2o(xA0.w));
        atomicMax(&smax[aA0 + 1], f2o(xA1.x));
        atomicMax(&smax[aA1 + 1], f2o(xA1.y));
        atomicMax(&smax[aA2 + 1], f2o(xA1.z));
        atomicMax(&smax[aA3 + 1], f2o(xA1.w));

        int aB0 = labB.x * STRIDE, aB1 = labB.y * STRIDE,
            aB2 = labB.z * STRIDE, aB3 = labB.w * STRIDE;
        atomicMax(&smax[aB0],     f2o(xB0.x));
        atomicMax(&smax[aB1],     f2o(xB0.y));
        atomicMax(&smax[aB2],     f2o(xB0.z));
        atomicMax(&smax[aB3],     f2o(xB0.w));
        atomicMax(&smax[aB0 + 1], f2o(xB1.x));
        atomicMax(&smax[aB1 + 1], f2o(xB1.y));
        atomicMax(&smax[aB2 + 1], f2o(xB1.z));
        atomicMax(&smax[aB3 + 1], f2o(xB1.w));
    }
    __syncthreads();

    // exclusive epilogue: this block owns out[b][c0..c0+CSUB)[*]
    float* outb = out + ((size_t)(b * C_ + c0)) * K_;
    for (int i = tid; i < K_ * CSUB; i += NTHREADS) {
        int c = i >> 10;                     // K_ = 1024
        int k = i & (K_ - 1);
        outb[c * K_ + k] = o2f(smax[k * STRIDE + c]);
    }
}

extern "C" void kernel_launch(void* const* d_in, const int* in_sizes, int n_in,
                              void* d_out, int out_size, void* d_ws, size_t ws_size,
                              hipStream_t stream) {
    const float* img = (const float*)d_in[0];
    const int*   spx = (const int*)d_in[1];
    float*       out = (float*)d_out;        // fp32 output, [B][C][K]
    dim3 grid(B_ * CGRP);                    // 512 blocks -> 2 blocks/CU
    hipLaunchKernelGGL(SupPixPool_25366076850473_kernel, grid, dim3(NTHREADS), 0, stream,
                       img, spx, out);
}